// Round 3
// baseline (81.163 us; speedup 1.0000x reference)
//
#include <hip/hip_runtime.h>

#define BATCH 4
#define SEQ   512
#define DIM   128

typedef _Float16 half8 __attribute__((ext_vector_type(8)));
typedef _Float16 half4 __attribute__((ext_vector_type(4)));
typedef float    f32x4 __attribute__((ext_vector_type(4)));

// load 8 consecutive f32 and convert to half8 (in-register, no staging)
__device__ __forceinline__ half8 ld8h(const float* __restrict__ p) {
    const float4 a = *(const float4*)p;
    const float4 b = *(const float4*)(p + 4);
    half8 h;
    h[0] = (_Float16)a.x; h[1] = (_Float16)a.y; h[2] = (_Float16)a.z; h[3] = (_Float16)a.w;
    h[4] = (_Float16)b.x; h[5] = (_Float16)b.y; h[6] = (_Float16)b.z; h[7] = (_Float16)b.w;
    return h;
}

// ---------------------------------------------------------------------------
// KA: fused prep + projections.
//  blocks [0,256): proj. Wave tile 16tok x 16col; block = 4 waves stacked in
//    tokens (64tok x 16col). f32->f16 conversion of x and W fragments is done
//    inline in registers (no x_h / W_h buffers, no extra kernel).
//    Epilogue (same math as R2, which passed at absmax 2e-3):
//      qout[b][tok][col]       = sigmoid(dq + bq)            (f32)
//      ekk[b][2c+0][tok] (f16) = exp(dk + bk)                (den operand)
//      ekk[b][2c+1][tok] (f16) = exp(dk + bk)*(dv + bv)      (num operand)
//  blocks [256,384): ep_h[i] = (f16)exp(pos[i]), 2048 elems/block.
// ---------------------------------------------------------------------------
__global__ __launch_bounds__(256) void KA(
    const float* __restrict__ x,
    const float* __restrict__ Wq, const float* __restrict__ bq,
    const float* __restrict__ Wk, const float* __restrict__ bk,
    const float* __restrict__ Wv, const float* __restrict__ bv,
    const float* __restrict__ pos,
    float* __restrict__ qout, _Float16* __restrict__ ekk,
    _Float16* __restrict__ ep_h)
{
    const int tid = threadIdx.x;
    const int bi  = blockIdx.x;

    if (bi >= 256) {
        // ---- ep conversion blocks ----
        const int i = ((bi - 256) * 256 + tid) * 8;
        const float4 p0 = *(const float4*)(pos + i);
        const float4 p1 = *(const float4*)(pos + i + 4);
        half8 h;
        h[0] = (_Float16)__expf(p0.x); h[1] = (_Float16)__expf(p0.y);
        h[2] = (_Float16)__expf(p0.z); h[3] = (_Float16)__expf(p0.w);
        h[4] = (_Float16)__expf(p1.x); h[5] = (_Float16)__expf(p1.y);
        h[6] = (_Float16)__expf(p1.z); h[7] = (_Float16)__expf(p1.w);
        *(half8*)(ep_h + i) = h;
        return;
    }

    // ---- proj blocks ----
    const int lane = tid & 63;
    const int wave = tid >> 6;
    const int l15  = lane & 15;
    const int quad = lane >> 4;

    const int n0 = (bi & 7) * 16;               // col tile
    const int m0 = (bi >> 3) * 64 + wave * 16;  // token-row tile (global 0..2047)

    const float* xa = x  + (m0 + l15) * DIM + quad * 8;
    const float* wq = Wq + (n0 + l15) * DIM + quad * 8;
    const float* wk = Wk + (n0 + l15) * DIM + quad * 8;
    const float* wv = Wv + (n0 + l15) * DIM + quad * 8;

    f32x4 aq = {0.f, 0.f, 0.f, 0.f};
    f32x4 ak = {0.f, 0.f, 0.f, 0.f};
    f32x4 av = {0.f, 0.f, 0.f, 0.f};

#pragma unroll
    for (int ks = 0; ks < 4; ++ks) {            // K = 128, 32 per step
        const half8 a  = ld8h(xa + ks * 32);
        const half8 b0 = ld8h(wq + ks * 32);
        const half8 b1 = ld8h(wk + ks * 32);
        const half8 b2 = ld8h(wv + ks * 32);
        aq = __builtin_amdgcn_mfma_f32_16x16x32_f16(a, b0, aq, 0, 0, 0);
        ak = __builtin_amdgcn_mfma_f32_16x16x32_f16(a, b1, ak, 0, 0, 0);
        av = __builtin_amdgcn_mfma_f32_16x16x32_f16(a, b2, av, 0, 0, 0);
    }

    const int c = n0 + l15;
    const float bqv = bq[c];
    const float bkv = bk[c];
    const float bvv = bv[c];

    const int mrow = m0 + quad * 4;   // first of 4 token rows this lane holds
    const int b    = mrow >> 9;       // /512 (all 4 rows same batch)
    const int tok  = mrow & 511;

    half4 eh, evh;
#pragma unroll
    for (int r = 0; r < 4; ++r) {
        const float e  = __expf(ak[r] + bkv);
        const float vv = av[r] + bvv;
        const float qv = 1.f / (1.f + __expf(-(aq[r] + bqv)));
        eh[r]  = (_Float16)e;
        evh[r] = (_Float16)(e * vv);
        qout[(b * SEQ + tok + r) * DIM + c] = qv;
    }
    *(half4*)(ekk + ((b * 256) + 2 * c + 0) * SEQ + tok) = eh;
    *(half4*)(ekk + ((b * 256) + 2 * c + 1) * SEQ + tok) = evh;
}

// ---------------------------------------------------------------------------
// KB: AFT core (MFMA, zero LDS). Per b: D[m][t] = sum_j ekk[m][j] * ep[t][j],
//   m in [0,256): even = den, odd = num (interleaved d pairs per lane).
// Wave tile 16m x 16t (1 MFMA / K-step, K=512 -> 16 steps).
// Block = 4 waves arranged 2m x 2t -> 32m x 32t.
// Grid = 4b x (256/32) x (512/32) = 512 blocks -> 8 waves/CU = 2/SIMD
// (2x the latency hiding of R2's 1/SIMD).
// Epilogue: out[b][t][d] = q * num / den.
// ---------------------------------------------------------------------------
__global__ __launch_bounds__(256) void KB(
    const _Float16* __restrict__ ekk,
    const _Float16* __restrict__ ep_h,
    const float* __restrict__ qout,
    float* __restrict__ out)
{
    const int tid  = threadIdx.x;
    const int lane = tid & 63;
    const int wave = tid >> 6;
    const int l15  = lane & 15;
    const int quad = lane >> 4;

    const int bi = blockIdx.x;
    const int b  = bi >> 7;
    const int mt = (bi >> 4) & 7;    // 0..7   (32-row m tile)
    const int tt = bi & 15;          // 0..15  (32-col t tile)

    const int m0 = mt * 32 + (wave & 1) * 16;   // [0,256)
    const int t0 = tt * 32 + (wave >> 1) * 16;  // [0,512)

    const _Float16* arow = ekk  + ((b * 256) + m0 + l15) * SEQ + quad * 8;
    const _Float16* brow = ep_h + (t0 + l15) * SEQ + quad * 8;

    f32x4 acc = {0.f, 0.f, 0.f, 0.f};

#pragma unroll
    for (int ks = 0; ks < 16; ++ks) {           // K = 512, 32 per step
        const half8 a  = *(const half8*)(arow + ks * 32);
        const half8 b8 = *(const half8*)(brow + ks * 32);
        acc = __builtin_amdgcn_mfma_f32_16x16x32_f16(a, b8, acc, 0, 0, 0);
    }

    // lane holds rows m0+quad*4+{0..3} = (den,num) for d0 and d0+1
    const int d0 = (m0 + quad * 4) >> 1;
    const int t  = t0 + l15;
    const float2 qv = *(const float2*)(qout + ((b * SEQ) + t) * DIM + d0);
    float2 o;
    o.x = qv.x * acc[1] / acc[0];
    o.y = qv.y * acc[3] / acc[2];
    *(float2*)(out + ((b * SEQ) + t) * DIM + d0) = o;
}

// ---------------------------------------------------------------------------
extern "C" void kernel_launch(void* const* d_in, const int* in_sizes, int n_in,
                              void* d_out, int out_size, void* d_ws, size_t ws_size,
                              hipStream_t stream) {
    const float* x   = (const float*)d_in[0];
    const float* Wq  = (const float*)d_in[1];
    const float* bq  = (const float*)d_in[2];
    const float* Wk  = (const float*)d_in[3];
    const float* bk  = (const float*)d_in[4];
    const float* Wv  = (const float*)d_in[5];
    const float* bv  = (const float*)d_in[6];
    const float* pos = (const float*)d_in[7];

    float* outp = (float*)d_out;
    char*  ws   = (char*)d_ws;

    _Float16* ekk  = (_Float16*)(ws);                   // 1 MB
    _Float16* ep_h = (_Float16*)(ws + (1024 << 10));    // 512 KB
    float*    qout = (float*)   (ws + (1536 << 10));    // 1 MB

    KA<<<384, 256, 0, stream>>>(x, Wq, bq, Wk, bk, Wv, bv, pos, qout, ekk, ep_h);
    KB<<<512, 256, 0, stream>>>(ekk, ep_h, qout, outp);
}